// Round 20
// baseline (486.811 us; speedup 1.0000x reference)
//
#include <hip/hip_runtime.h>
#include <hip/hip_bf16.h>
#include <math.h>

// Problem constants (B,N,D,H,E) = (32,512,512,8,4), HD=64
constexpr int CB = 32, CN = 512, CD = 512, CH = 8, CHD = 64;
constexpr float LN_EPS = 1e-3f;

typedef _Float16 half8 __attribute__((ext_vector_type(8)));
typedef float f32x4 __attribute__((ext_vector_type(4)));

__device__ __forceinline__ void async16(const void* g, void* l) {
    __builtin_amdgcn_global_load_lds((const __attribute__((address_space(1))) void*)g,
                                     (__attribute__((address_space(3))) void*)l, 16, 0, 0);
}

// ---------------- weight transpose + fp32->f16: in[K][N] -> out[N][K] ------
// SCALE: multiply by g[k] while transposing (mid-LN gain folded into W').
template<bool SCALE>
__global__ __launch_bounds__(256) void transpose_f16(const float* __restrict__ in,
                                                     const float* __restrict__ g,
                                                     _Float16* __restrict__ out,
                                                     int K, int N) {
    __shared__ float t[32][33];
    const int tx = threadIdx.x % 32, ty = threadIdx.x / 32;
    const int n0 = blockIdx.x * 32, k0 = blockIdx.y * 32;
#pragma unroll
    for (int i = 0; i < 4; ++i)
        t[ty + i * 8][tx] = in[(size_t)(k0 + ty + i * 8) * N + n0 + tx];
    __syncthreads();
    const float gs = SCALE ? g[k0 + tx] : 1.0f;
#pragma unroll
    for (int i = 0; i < 4; ++i)
        out[(size_t)(n0 + ty + i * 8) * K + k0 + tx] = (_Float16)(t[tx][ty + i * 8] * gs);
}

// ---------------- parallel colsum: S1[n]+=sum_c g[c]*w2[c][n], S2 same w/ be
// grid (2, 8): block x covers 256 consecutive n (coalesced), y a 256-c stripe.
__global__ __launch_bounds__(256) void colsum_w2(const float* __restrict__ w2,
        const float* __restrict__ g, const float* __restrict__ be,
        float* __restrict__ S1, float* __restrict__ S2) {
    const int n = blockIdx.x * 256 + threadIdx.x;
    const int c0 = blockIdx.y * 256;
    float s1 = 0.f, s2 = 0.f;
    for (int c = c0; c < c0 + 256; ++c) {
        const float w = w2[(size_t)c * CD + n];
        s1 += g[c] * w;
        s2 += be[c] * w;
    }
    atomicAdd(&S1[n], s1);
    atomicAdd(&S2[n], s2);
}

// ---------------- LayerNorm, wave per row -----------------------------------
template<int WIDTH, bool IN_F16, bool OUT_F16, bool ADDRES>
__global__ __launch_bounds__(256) void ln2_kernel(const void* __restrict__ in_,
        const float* __restrict__ g, const float* __restrict__ be,
        const float* __restrict__ res, void* __restrict__ out_) {
    constexpr int NPL = WIDTH / 64;
    const int row = blockIdx.x * 4 + (threadIdx.x >> 6);
    const int lane = threadIdx.x & 63;
    const int c0 = lane * NPL;
    float v[NPL];
    if (IN_F16) {
        const _Float16* p = (const _Float16*)in_ + (size_t)row * WIDTH + c0;
#pragma unroll
        for (int i = 0; i < NPL / 8; ++i) {
            half8 u = *(const half8*)(p + i * 8);
#pragma unroll
            for (int j = 0; j < 8; ++j) v[i * 8 + j] = (float)u[j];
        }
    } else {
        const float* p = (const float*)in_ + (size_t)row * WIDTH + c0;
#pragma unroll
        for (int i = 0; i < NPL / 4; ++i) {
            float4 u = *(const float4*)(p + i * 4);
            v[i * 4 + 0] = u.x; v[i * 4 + 1] = u.y; v[i * 4 + 2] = u.z; v[i * 4 + 3] = u.w;
        }
    }
    float s1 = 0.f, s2 = 0.f;
#pragma unroll
    for (int i = 0; i < NPL; ++i) { s1 += v[i]; s2 += v[i] * v[i]; }
#pragma unroll
    for (int off = 1; off < 64; off <<= 1) { s1 += __shfl_xor(s1, off); s2 += __shfl_xor(s2, off); }
    const float mean = s1 * (1.0f / WIDTH);
    const float var = s2 * (1.0f / WIDTH) - mean * mean;
    const float rstd = rsqrtf(var + LN_EPS);

    float ov[NPL];
#pragma unroll
    for (int i = 0; i < NPL / 4; ++i) {
        float4 gv = *(const float4*)(g + c0 + i * 4);
        float4 bv = *(const float4*)(be + c0 + i * 4);
        ov[i * 4 + 0] = (v[i * 4 + 0] - mean) * rstd * gv.x + bv.x;
        ov[i * 4 + 1] = (v[i * 4 + 1] - mean) * rstd * gv.y + bv.y;
        ov[i * 4 + 2] = (v[i * 4 + 2] - mean) * rstd * gv.z + bv.z;
        ov[i * 4 + 3] = (v[i * 4 + 3] - mean) * rstd * gv.w + bv.w;
    }
    if (ADDRES) {
        const float* rp = res + (size_t)row * WIDTH + c0;
#pragma unroll
        for (int i = 0; i < NPL / 4; ++i) {
            float4 rv = *(const float4*)(rp + i * 4);
            ov[i * 4 + 0] += rv.x; ov[i * 4 + 1] += rv.y; ov[i * 4 + 2] += rv.z; ov[i * 4 + 3] += rv.w;
        }
    }
    if (OUT_F16) {
        _Float16* po = (_Float16*)out_ + (size_t)row * WIDTH + c0;
#pragma unroll
        for (int i = 0; i < NPL / 8; ++i) {
            half8 hv;
#pragma unroll
            for (int j = 0; j < 8; ++j) hv[j] = (_Float16)ov[i * 8 + j];
            *(half8*)(po + i * 8) = hv;
        }
    } else {
        float* po = (float*)out_ + (size_t)row * WIDTH + c0;
#pragma unroll
        for (int i = 0; i < NPL / 4; ++i) {
            float4 w = make_float4(ov[i * 4 + 0], ov[i * 4 + 1], ov[i * 4 + 2], ov[i * 4 + 3]);
            *(float4*)(po + i * 4) = w;
        }
    }
}

// ---------------- fused: attended = LN(o2)+x ; f = LN(attended) -------------
__global__ __launch_bounds__(256) void ln_post_ffn(const _Float16* __restrict__ o2,
        const float* __restrict__ x,
        const float* __restrict__ g_post, const float* __restrict__ be_post,
        const float* __restrict__ g_ffn, const float* __restrict__ be_ffn,
        float* __restrict__ attended, _Float16* __restrict__ f) {
    constexpr int NPL = 8;
    const int row = blockIdx.x * 4 + (threadIdx.x >> 6);
    const int lane = threadIdx.x & 63;
    const int c0 = lane * NPL;
    float v[NPL], xv[NPL];
    {
        half8 u = *(const half8*)(o2 + (size_t)row * CD + c0);
#pragma unroll
        for (int j = 0; j < 8; ++j) v[j] = (float)u[j];
        float4 a = *(const float4*)(x + (size_t)row * CD + c0);
        float4 b = *(const float4*)(x + (size_t)row * CD + c0 + 4);
        xv[0] = a.x; xv[1] = a.y; xv[2] = a.z; xv[3] = a.w;
        xv[4] = b.x; xv[5] = b.y; xv[6] = b.z; xv[7] = b.w;
    }
    float s1 = 0.f, s2 = 0.f;
#pragma unroll
    for (int i = 0; i < NPL; ++i) { s1 += v[i]; s2 += v[i] * v[i]; }
#pragma unroll
    for (int off = 1; off < 64; off <<= 1) { s1 += __shfl_xor(s1, off); s2 += __shfl_xor(s2, off); }
    float mean = s1 * (1.0f / CD);
    float rstd = rsqrtf(s2 * (1.0f / CD) - mean * mean + LN_EPS);
    float av[NPL];
#pragma unroll
    for (int i = 0; i < NPL; ++i)
        av[i] = (v[i] - mean) * rstd * g_post[c0 + i] + be_post[c0 + i] + xv[i];
    {
        float4 w0 = make_float4(av[0], av[1], av[2], av[3]);
        float4 w1 = make_float4(av[4], av[5], av[6], av[7]);
        *(float4*)(attended + (size_t)row * CD + c0) = w0;
        *(float4*)(attended + (size_t)row * CD + c0 + 4) = w1;
    }
    s1 = 0.f; s2 = 0.f;
#pragma unroll
    for (int i = 0; i < NPL; ++i) { s1 += av[i]; s2 += av[i] * av[i]; }
#pragma unroll
    for (int off = 1; off < 64; off <<= 1) { s1 += __shfl_xor(s1, off); s2 += __shfl_xor(s2, off); }
    mean = s1 * (1.0f / CD);
    rstd = rsqrtf(s2 * (1.0f / CD) - mean * mean + LN_EPS);
    half8 hv;
#pragma unroll
    for (int i = 0; i < NPL; ++i)
        hv[i] = (_Float16)((av[i] - mean) * rstd * g_ffn[c0 + i] + be_ffn[c0 + i]);
    *(half8*)(f + (size_t)row * CD + c0) = hv;
}

// ---------------- f16 MFMA GEMM, double-buffered + counted vmcnt ------------
// STATS: accumulate per-row sum/sumsq of outputs via shfl-reduce + atomics.
// MIDLN: folded mid-LN affine: out = rho*acc - mu*rho*S1[n] + S2[n] + bias (+res).
template<bool GELU, bool RES, bool OUT_F16, bool STATS, bool MIDLN>
__global__ __launch_bounds__(256) void gemm_f16(const _Float16* __restrict__ A,
        const _Float16* __restrict__ Wt, const float* __restrict__ bias,
        const float* __restrict__ res, void* __restrict__ Cout,
        int M, int N, int K,
        float* __restrict__ rowsum, float* __restrict__ rowsumsq,
        const float* __restrict__ S1, const float* __restrict__ S2) {
    __shared__ __align__(16) char As[2][16384];
    __shared__ __align__(16) char Bs[2][16384];
    const int tid = threadIdx.x;
    const int nbx = N >> 7;
    const int nwg = (M >> 7) * nbx;
    int gb = blockIdx.x;
    gb = (gb & 7) * (nwg >> 3) + (gb >> 3);   // XCD swizzle (nwg % 8 == 0)
    const int by = gb / nbx, bx = gb % nbx;

    const int lane = tid & 63;
    const int wv = tid >> 6;
    const int rsub = lane >> 3;
    const int slot = lane & 7;
    const int chunk = slot ^ rsub;
    const _Float16* Abase = A + (size_t)(by * 128) * K + chunk * 8;
    const _Float16* Bbase = Wt + (size_t)(bx * 128) * K + chunk * 8;

    const int wm = wv >> 1, wn = wv & 1;
    const int lrow = lane & 15;
    const int lk = lane >> 4;
    const int xorv = lane & 7;
    const int aRowB = (wm * 64 + lrow) * 128;
    const int bRowB = (wn * 64 + lrow) * 128;

    f32x4 acc[4][4] = {};

    auto stage = [&](int buf, int k0) {
#pragma unroll
        for (int t = 0; t < 4; ++t) {
            const int rowb = t * 32 + wv * 8;
            async16(Abase + (size_t)(rowb + rsub) * K + k0, As[buf] + rowb * 128);
            async16(Bbase + (size_t)(rowb + rsub) * K + k0, Bs[buf] + rowb * 128);
        }
    };

    const int nsteps = K >> 6;
    stage(0, 0);
    for (int step = 0; step < nsteps; ++step) {
        const int cur = step & 1;
        if (step + 1 < nsteps) {
            stage(cur ^ 1, (step + 1) * 64);
            asm volatile("s_waitcnt vmcnt(8)" ::: "memory");
        } else {
            asm volatile("s_waitcnt vmcnt(0)" ::: "memory");
        }
        __builtin_amdgcn_s_barrier();
#pragma unroll
        for (int kk = 0; kk < 2; ++kk) {
            const int sa = ((kk * 4 + lk) ^ xorv) << 4;
            half8 af[4], bf[4];
#pragma unroll
            for (int mi = 0; mi < 4; ++mi) af[mi] = *(const half8*)(As[cur] + aRowB + mi * 2048 + sa);
#pragma unroll
            for (int ni = 0; ni < 4; ++ni) bf[ni] = *(const half8*)(Bs[cur] + bRowB + ni * 2048 + sa);
#pragma unroll
            for (int mi = 0; mi < 4; ++mi)
#pragma unroll
                for (int ni = 0; ni < 4; ++ni)
                    acc[mi][ni] = __builtin_amdgcn_mfma_f32_16x16x32_f16(af[mi], bf[ni], acc[mi][ni], 0, 0, 0);
        }
        asm volatile("s_waitcnt lgkmcnt(0)" ::: "memory");
        __builtin_amdgcn_s_barrier();
    }

    const int lr4 = (lane >> 4) * 4;
    const int lc = lane & 15;

    float muv[4][4], rhov[4][4];   // MIDLN per-row stats
    if (MIDLN) {
#pragma unroll
        for (int mi = 0; mi < 4; ++mi)
#pragma unroll
            for (int r = 0; r < 4; ++r) {
                const int row = by * 128 + wm * 64 + mi * 16 + lr4 + r;
                const float mu = rowsum[row] * (1.0f / (4 * CD));
                const float var = rowsumsq[row] * (1.0f / (4 * CD)) - mu * mu;
                const float rho = rsqrtf(var + LN_EPS);
                muv[mi][r] = mu * rho;
                rhov[mi][r] = rho;
            }
    }

    float st1[4][4] = {}, st2[4][4] = {};
#pragma unroll
    for (int ni = 0; ni < 4; ++ni) {
        const int colg = bx * 128 + wn * 64 + ni * 16 + lc;
        const float bv = bias[colg];
        const float s1v = MIDLN ? S1[colg] : 0.f;
        const float s2v = MIDLN ? S2[colg] : 0.f;
#pragma unroll
        for (int mi = 0; mi < 4; ++mi) {
            const int rowg = by * 128 + wm * 64 + mi * 16 + lr4;
#pragma unroll
            for (int r = 0; r < 4; ++r) {
                float v;
                if (MIDLN) {
                    v = rhov[mi][r] * acc[mi][ni][r] - muv[mi][r] * s1v + s2v + bv;
                } else {
                    v = acc[mi][ni][r] + bv;
                    if (GELU) v = 0.5f * v * (1.0f + erff(v * 0.70710678118654752440f));
                }
                if (STATS) { st1[mi][r] += v; st2[mi][r] += v * v; }
                if (RES) v += res[(size_t)(rowg + r) * N + colg];
                if (OUT_F16) ((_Float16*)Cout)[(size_t)(rowg + r) * N + colg] = (_Float16)v;
                else ((float*)Cout)[(size_t)(rowg + r) * N + colg] = v;
            }
        }
    }
    if (STATS) {
#pragma unroll
        for (int mi = 0; mi < 4; ++mi)
#pragma unroll
            for (int r = 0; r < 4; ++r) {
#pragma unroll
                for (int off = 1; off < 16; off <<= 1) {
                    st1[mi][r] += __shfl_xor(st1[mi][r], off);
                    st2[mi][r] += __shfl_xor(st2[mi][r], off);
                }
            }
        if (lc == 0) {
#pragma unroll
            for (int mi = 0; mi < 4; ++mi)
#pragma unroll
                for (int r = 0; r < 4; ++r) {
                    const int row = by * 128 + wm * 64 + mi * 16 + lr4 + r;
                    atomicAdd(&rowsum[row], st1[mi][r]);
                    atomicAdd(&rowsumsq[row], st2[mi][r]);
                }
        }
    }
}

// ---------------- MFMA flash attention (session-best, frozen R19) -----------
__global__ __launch_bounds__(256) void attn_mfma(
        const _Float16* __restrict__ qkv, const float* __restrict__ inter,
        const int* __restrict__ mask, _Float16* __restrict__ o) {
    const int bid = blockIdx.x;
    const int xcd = bid & 7;
    const int s = bid >> 3;
    const int h = s & 7;
    const int qt = (s >> 3) & 7;
    const int b = (s >> 6) * 8 + xcd;
    const int tid = threadIdx.x;
    const int lane = tid & 63;
    const int w = tid >> 6;
    const int l15 = lane & 15, l4 = lane >> 4;

    __shared__ __align__(16) char Ks[8192];
    __shared__ __align__(16) char Vt[8192];
    __shared__ __align__(16) char Ps[8192];

    constexpr size_t QKVROW = 1536;
    half8 q0, q1;
    {
        const _Float16* qrow_g = qkv + (size_t)(b * CN + qt * 64 + w * 16 + l15) * QKVROW + h * 64;
        q0 = *(const half8*)(qrow_g + l4 * 8);
        q1 = *(const half8*)(qrow_g + 32 + l4 * 8);
    }

    f32x4 acc_o[4] = {};
    float m_run[4] = {-3e38f, -3e38f, -3e38f, -3e38f};
    float l_run[4] = {0.f, 0.f, 0.f, 0.f};

    const int qg0 = qt * 64 + w * 16 + l4 * 4;
    const float* interB[4];
    const int* maskB[4];
#pragma unroll
    for (int r = 0; r < 4; ++r) {
        interB[r] = inter + ((size_t)(b * CN + qg0 + r) * CN) * CH + h;
        maskB[r]  = mask + (size_t)(b * CN + qg0 + r) * CN;
    }

    for (int mt = 0; mt < 8; ++mt) {
        __syncthreads();
        const _Float16* Kg = qkv + (size_t)(b * CN + mt * 64) * QKVROW + 512 + h * 64;
        const _Float16* Vg = Kg + 512;
#pragma unroll
        for (int p = 0; p < 2; ++p) {
            const int f = tid + 256 * p;
            const int r = f >> 3, c = f & 7;
            half8 kv = *(const half8*)(Kg + (size_t)r * QKVROW + c * 8);
            *(half8*)(Ks + r * 128 + ((c ^ (r & 7)) << 4)) = kv;
        }
#pragma unroll
        for (int p = 0; p < 2; ++p) {
            const int f = tid + 256 * p;
            const int m = f >> 3, dc = f & 7;
            half8 vv = *(const half8*)(Vg + (size_t)m * QKVROW + dc * 8);
            const int mc = m >> 3, mo = m & 7;
#pragma unroll
            for (int j = 0; j < 8; ++j) {
                const int d = dc * 8 + j;
                *(_Float16*)(Vt + d * 128 + ((mc ^ (d & 7) ^ dc) << 4) + mo * 2) = vv[j];
            }
        }
        float iv[4][4];
#pragma unroll
        for (int r = 0; r < 4; ++r)
#pragma unroll
            for (int mi = 0; mi < 4; ++mi) {
                const int m = mt * 64 + mi * 16 + l15;
                const float bvv = interB[r][(size_t)m * CH];
                iv[r][mi] = bvv + (maskB[r][m] ? 0.f : -1e9f);
            }
        __syncthreads();

        f32x4 acc_s[4] = {};
#pragma unroll
        for (int step = 0; step < 2; ++step) {
            const half8 aq = step == 0 ? q0 : q1;
            const int ch = step * 4 + l4;
#pragma unroll
            for (int mi = 0; mi < 4; ++mi) {
                const int mrow = mi * 16 + l15;
                half8 bk = *(const half8*)(Ks + mrow * 128 + ((ch ^ (mrow & 7)) << 4));
                acc_s[mi] = __builtin_amdgcn_mfma_f32_16x16x32_f16(aq, bk, acc_s[mi], 0, 0, 0);
            }
        }
#pragma unroll
        for (int r = 0; r < 4; ++r) {
            float pv[4];
            float rmax = -3e38f;
#pragma unroll
            for (int mi = 0; mi < 4; ++mi) {
                float sv = acc_s[mi][r] * 0.125f + iv[r][mi];
                pv[mi] = sv;
                rmax = fmaxf(rmax, sv);
            }
#pragma unroll
            for (int off = 1; off < 16; off <<= 1) rmax = fmaxf(rmax, __shfl_xor(rmax, off));
            const float nm = fmaxf(m_run[r], rmax);
            const float fac = __expf(m_run[r] - nm);
            m_run[r] = nm;
            float ps = 0.f;
#pragma unroll
            for (int mi = 0; mi < 4; ++mi) { float e = __expf(pv[mi] - nm); pv[mi] = e; ps += e; }
#pragma unroll
            for (int off = 1; off < 16; off <<= 1) ps += __shfl_xor(ps, off);
            l_run[r] = l_run[r] * fac + ps;
#pragma unroll
            for (int di = 0; di < 4; ++di) acc_o[di][r] *= fac;
            const int qrow = w * 16 + l4 * 4 + r;
#pragma unroll
            for (int mi = 0; mi < 4; ++mi) {
                const int m = mi * 16 + l15;
                *(_Float16*)(Ps + qrow * 128 + (((m >> 3) ^ (qrow & 7)) << 4) + (m & 7) * 2) = (_Float16)pv[mi];
            }
        }
#pragma unroll
        for (int step = 0; step < 2; ++step) {
            const int qrow = w * 16 + l15;
            const int ch = step * 4 + l4;
            half8 ap = *(const half8*)(Ps + qrow * 128 + ((ch ^ (qrow & 7)) << 4));
#pragma unroll
            for (int di = 0; di < 4; ++di) {
                const int drow = di * 16 + l15;
                half8 bv = *(const half8*)(Vt + drow * 128 + ((ch ^ (drow & 7) ^ (drow >> 3)) << 4));
                acc_o[di] = __builtin_amdgcn_mfma_f32_16x16x32_f16(ap, bv, acc_o[di], 0, 0, 0);
            }
        }
    }
    _Float16* orow = o + (size_t)(b * CN + qt * 64 + w * 16 + l4 * 4) * CD + h * 64 + l15;
#pragma unroll
    for (int r = 0; r < 4; ++r) {
        const float inv = 1.0f / l_run[r];
#pragma unroll
        for (int di = 0; di < 4; ++di)
            orow[(size_t)r * CD + di * 16] = (_Float16)(acc_o[di][r] * inv);
    }
}

// ---------------- driver ----------------------------------------------------
extern "C" void kernel_launch(void* const* d_in, const int* in_sizes, int n_in,
                              void* d_out, int out_size, void* d_ws, size_t ws_size,
                              hipStream_t stream) {
    const float* x      = (const float*)d_in[0];
    const int*   mask   = (const int*)d_in[1];
    const float* inter  = (const float*)d_in[2];
    const float* w_qkv  = (const float*)d_in[3];
    const float* b_qkv  = (const float*)d_in[4];
    const float* w_out  = (const float*)d_in[5];
    const float* b_out  = (const float*)d_in[6];
    const float* w1     = (const float*)d_in[7];
    const float* b1     = (const float*)d_in[8];
    const float* w2     = (const float*)d_in[9];
    const float* b2     = (const float*)d_in[10];
    const float* g_pre  = (const float*)d_in[11];
    const float* be_pre = (const float*)d_in[12];
    const float* g_post = (const float*)d_in[13];
    const float* be_post= (const float*)d_in[14];
    const float* g_ffn  = (const float*)d_in[15];
    const float* be_ffn = (const float*)d_in[16];
    const float* g_mid  = (const float*)d_in[17];
    const float* be_mid = (const float*)d_in[18];
    float* out = (float*)d_out;

    char* ws = (char*)d_ws;
    const size_t MB = 1ull << 20;
    _Float16* wt_qkv = (_Float16*)(ws + 0 * MB);
    _Float16* wt_out = (_Float16*)(ws + 2 * MB);
    _Float16* wt_w1  = (_Float16*)(ws + 3 * MB);
    _Float16* wt_w2  = (_Float16*)(ws + 5 * MB);   // g_mid-scaled W'
    float*    attended = (float*)(ws + 8 * MB);    // [8,40) fp32
    _Float16* o2h    = (_Float16*)(ws + 40 * MB);  // [40,56) f16
    float*    rowsum   = (float*)(ws + 56 * MB);            // 64KB
    float*    rowsumsq = (float*)(ws + 56 * MB + (64 << 10));// 64KB
    float*    S1buf    = (float*)(ws + 56 * MB + (128 << 10));// 2KB
    float*    S2buf    = (float*)(ws + 56 * MB + (130 << 10));// 2KB
    _Float16* f1b    = (_Float16*)(ws + 64 * MB);  // [64,128) f16 [M,2048]
    _Float16* qkvb   = (_Float16*)(ws + 128 * MB); // [128,176)
    _Float16* hb     = (_Float16*)(ws + 176 * MB); // [176,192)
    _Float16* ob     = (_Float16*)(ws + 192 * MB); // [192,208)
    _Float16* fb     = (_Float16*)(ws + 208 * MB); // [208,224)

    const int M = CB * CN;  // 16384

    // zero stats/colsum accumulators (132KB), then weight prep
    hipMemsetAsync(rowsum, 0, 132 << 10, stream);
    transpose_f16<false><<<dim3(1536 / 32, 512 / 32), 256, 0, stream>>>(w_qkv, nullptr, wt_qkv, 512, 1536);
    transpose_f16<false><<<dim3(512 / 32, 512 / 32), 256, 0, stream>>>(w_out, nullptr, wt_out, 512, 512);
    transpose_f16<false><<<dim3(2048 / 32, 512 / 32), 256, 0, stream>>>(w1, nullptr, wt_w1, 512, 2048);
    transpose_f16<true><<<dim3(512 / 32, 2048 / 32), 256, 0, stream>>>(w2, g_mid, wt_w2, 2048, 512);
    colsum_w2<<<dim3(2, 8), 256, 0, stream>>>(w2, g_mid, be_mid, S1buf, S2buf);

    // 1. h = LN(x) -> f16
    ln2_kernel<512, false, true, false><<<M / 4, 256, 0, stream>>>(x, g_pre, be_pre, nullptr, hb);
    // 2. qkv = h @ w_qkv + b_qkv -> f16
    gemm_f16<false, false, true, false, false><<<(M / 128) * (1536 / 128), 256, 0, stream>>>(
        hb, wt_qkv, b_qkv, nullptr, qkvb, M, 1536, 512, nullptr, nullptr, nullptr, nullptr);
    // 3. attention (frozen R19) -> o f16
    attn_mfma<<<CB * 8 * 8, 256, 0, stream>>>(qkvb, inter, mask, ob);
    // 4. o2 = o @ w_out + b_out -> f16
    gemm_f16<false, false, true, false, false><<<(M / 128) * (512 / 128), 256, 0, stream>>>(
        ob, wt_out, b_out, nullptr, o2h, M, 512, 512, nullptr, nullptr, nullptr, nullptr);
    // 5+6. attended = LN(o2)+x (fp32); f = LN(attended) (f16)
    ln_post_ffn<<<M / 4, 256, 0, stream>>>(o2h, x, g_post, be_post, g_ffn, be_ffn, attended, fb);
    // 7. f1 = gelu(f @ w1 + b1) -> f16, + per-row stats via shfl+atomics
    gemm_f16<true, false, true, true, false><<<(M / 128) * (2048 / 128), 256, 0, stream>>>(
        fb, wt_w1, b1, nullptr, f1b, M, 2048, 512, rowsum, rowsumsq, nullptr, nullptr);
    // 8. (mid-LN folded into step 9)
    // 9. out = LN_mid(f1) @ w2 + b2 + attended -> fp32 (folded affine)
    gemm_f16<false, true, false, false, true><<<(M / 128) * (512 / 128), 256, 0, stream>>>(
        f1b, wt_w2, b2, attended, out, M, 512, 2048, rowsum, rowsumsq, S1buf, S2buf);
}

// Round 21
// 438.203 us; speedup vs baseline: 1.1109x; 1.1109x over previous
//
#include <hip/hip_runtime.h>
#include <hip/hip_bf16.h>
#include <math.h>

// Problem constants (B,N,D,H,E) = (32,512,512,8,4), HD=64
constexpr int CB = 32, CN = 512, CD = 512, CH = 8, CHD = 64;
constexpr float LN_EPS = 1e-3f;

typedef _Float16 half8 __attribute__((ext_vector_type(8)));
typedef float f32x4 __attribute__((ext_vector_type(4)));

__device__ __forceinline__ void async16(const void* g, void* l) {
    __builtin_amdgcn_global_load_lds((const __attribute__((address_space(1))) void*)g,
                                     (__attribute__((address_space(3))) void*)l, 16, 0, 0);
}

// ---------------- weight transpose + fp32->f16: in[K][N] -> out[N][K] ------
__global__ __launch_bounds__(256) void transpose_f16(const float* __restrict__ in,
                                                     _Float16* __restrict__ out,
                                                     int K, int N) {
    __shared__ float t[32][33];
    const int tx = threadIdx.x % 32, ty = threadIdx.x / 32;
    const int n0 = blockIdx.x * 32, k0 = blockIdx.y * 32;
#pragma unroll
    for (int i = 0; i < 4; ++i)
        t[ty + i * 8][tx] = in[(size_t)(k0 + ty + i * 8) * N + n0 + tx];
    __syncthreads();
#pragma unroll
    for (int i = 0; i < 4; ++i)
        out[(size_t)(n0 + ty + i * 8) * K + k0 + tx] = (_Float16)t[tx][ty + i * 8];
}

// ---------------- LayerNorm, wave per row -----------------------------------
template<int WIDTH, bool IN_F16, bool OUT_F16, bool ADDRES>
__global__ __launch_bounds__(256) void ln2_kernel(const void* __restrict__ in_,
        const float* __restrict__ g, const float* __restrict__ be,
        const float* __restrict__ res, void* __restrict__ out_) {
    constexpr int NPL = WIDTH / 64;
    const int row = blockIdx.x * 4 + (threadIdx.x >> 6);
    const int lane = threadIdx.x & 63;
    const int c0 = lane * NPL;
    float v[NPL];
    if (IN_F16) {
        const _Float16* p = (const _Float16*)in_ + (size_t)row * WIDTH + c0;
#pragma unroll
        for (int i = 0; i < NPL / 8; ++i) {
            half8 u = *(const half8*)(p + i * 8);
#pragma unroll
            for (int j = 0; j < 8; ++j) v[i * 8 + j] = (float)u[j];
        }
    } else {
        const float* p = (const float*)in_ + (size_t)row * WIDTH + c0;
#pragma unroll
        for (int i = 0; i < NPL / 4; ++i) {
            float4 u = *(const float4*)(p + i * 4);
            v[i * 4 + 0] = u.x; v[i * 4 + 1] = u.y; v[i * 4 + 2] = u.z; v[i * 4 + 3] = u.w;
        }
    }
    float s1 = 0.f, s2 = 0.f;
#pragma unroll
    for (int i = 0; i < NPL; ++i) { s1 += v[i]; s2 += v[i] * v[i]; }
#pragma unroll
    for (int off = 1; off < 64; off <<= 1) { s1 += __shfl_xor(s1, off); s2 += __shfl_xor(s2, off); }
    const float mean = s1 * (1.0f / WIDTH);
    const float var = s2 * (1.0f / WIDTH) - mean * mean;
    const float rstd = rsqrtf(var + LN_EPS);

    float ov[NPL];
#pragma unroll
    for (int i = 0; i < NPL / 4; ++i) {
        float4 gv = *(const float4*)(g + c0 + i * 4);
        float4 bv = *(const float4*)(be + c0 + i * 4);
        ov[i * 4 + 0] = (v[i * 4 + 0] - mean) * rstd * gv.x + bv.x;
        ov[i * 4 + 1] = (v[i * 4 + 1] - mean) * rstd * gv.y + bv.y;
        ov[i * 4 + 2] = (v[i * 4 + 2] - mean) * rstd * gv.z + bv.z;
        ov[i * 4 + 3] = (v[i * 4 + 3] - mean) * rstd * gv.w + bv.w;
    }
    if (ADDRES) {
        const float* rp = res + (size_t)row * WIDTH + c0;
#pragma unroll
        for (int i = 0; i < NPL / 4; ++i) {
            float4 rv = *(const float4*)(rp + i * 4);
            ov[i * 4 + 0] += rv.x; ov[i * 4 + 1] += rv.y; ov[i * 4 + 2] += rv.z; ov[i * 4 + 3] += rv.w;
        }
    }
    if (OUT_F16) {
        _Float16* po = (_Float16*)out_ + (size_t)row * WIDTH + c0;
#pragma unroll
        for (int i = 0; i < NPL / 8; ++i) {
            half8 hv;
#pragma unroll
            for (int j = 0; j < 8; ++j) hv[j] = (_Float16)ov[i * 8 + j];
            *(half8*)(po + i * 8) = hv;
        }
    } else {
        float* po = (float*)out_ + (size_t)row * WIDTH + c0;
#pragma unroll
        for (int i = 0; i < NPL / 4; ++i) {
            float4 w = make_float4(ov[i * 4 + 0], ov[i * 4 + 1], ov[i * 4 + 2], ov[i * 4 + 3]);
            *(float4*)(po + i * 4) = w;
        }
    }
}

// ---------------- fused: attended = LN(o2)+x ; f = LN(attended) -------------
__global__ __launch_bounds__(256) void ln_post_ffn(const _Float16* __restrict__ o2,
        const float* __restrict__ x,
        const float* __restrict__ g_post, const float* __restrict__ be_post,
        const float* __restrict__ g_ffn, const float* __restrict__ be_ffn,
        float* __restrict__ attended, _Float16* __restrict__ f) {
    constexpr int NPL = 8;
    const int row = blockIdx.x * 4 + (threadIdx.x >> 6);
    const int lane = threadIdx.x & 63;
    const int c0 = lane * NPL;
    float v[NPL], xv[NPL];
    {
        half8 u = *(const half8*)(o2 + (size_t)row * CD + c0);
#pragma unroll
        for (int j = 0; j < 8; ++j) v[j] = (float)u[j];
        float4 a = *(const float4*)(x + (size_t)row * CD + c0);
        float4 b = *(const float4*)(x + (size_t)row * CD + c0 + 4);
        xv[0] = a.x; xv[1] = a.y; xv[2] = a.z; xv[3] = a.w;
        xv[4] = b.x; xv[5] = b.y; xv[6] = b.z; xv[7] = b.w;
    }
    float s1 = 0.f, s2 = 0.f;
#pragma unroll
    for (int i = 0; i < NPL; ++i) { s1 += v[i]; s2 += v[i] * v[i]; }
#pragma unroll
    for (int off = 1; off < 64; off <<= 1) { s1 += __shfl_xor(s1, off); s2 += __shfl_xor(s2, off); }
    float mean = s1 * (1.0f / CD);
    float rstd = rsqrtf(s2 * (1.0f / CD) - mean * mean + LN_EPS);
    float av[NPL];
#pragma unroll
    for (int i = 0; i < NPL; ++i)
        av[i] = (v[i] - mean) * rstd * g_post[c0 + i] + be_post[c0 + i] + xv[i];
    {
        float4 w0 = make_float4(av[0], av[1], av[2], av[3]);
        float4 w1 = make_float4(av[4], av[5], av[6], av[7]);
        *(float4*)(attended + (size_t)row * CD + c0) = w0;
        *(float4*)(attended + (size_t)row * CD + c0 + 4) = w1;
    }
    s1 = 0.f; s2 = 0.f;
#pragma unroll
    for (int i = 0; i < NPL; ++i) { s1 += av[i]; s2 += av[i] * av[i]; }
#pragma unroll
    for (int off = 1; off < 64; off <<= 1) { s1 += __shfl_xor(s1, off); s2 += __shfl_xor(s2, off); }
    mean = s1 * (1.0f / CD);
    rstd = rsqrtf(s2 * (1.0f / CD) - mean * mean + LN_EPS);
    half8 hv;
#pragma unroll
    for (int i = 0; i < NPL; ++i)
        hv[i] = (_Float16)((av[i] - mean) * rstd * g_ffn[c0 + i] + be_ffn[c0 + i]);
    *(half8*)(f + (size_t)row * CD + c0) = hv;
}

// ---------------- f16 MFMA GEMM, double-buffered + counted vmcnt ------------
template<bool GELU, bool RES, bool OUT_F16>
__global__ __launch_bounds__(256) void gemm_f16(const _Float16* __restrict__ A,
        const _Float16* __restrict__ Wt, const float* __restrict__ bias,
        const float* __restrict__ res, void* __restrict__ Cout,
        int M, int N, int K) {
    __shared__ __align__(16) char As[2][16384];
    __shared__ __align__(16) char Bs[2][16384];
    const int tid = threadIdx.x;
    const int nbx = N >> 7;
    const int nwg = (M >> 7) * nbx;
    int gb = blockIdx.x;
    gb = (gb & 7) * (nwg >> 3) + (gb >> 3);   // XCD swizzle (nwg % 8 == 0)
    const int by = gb / nbx, bx = gb % nbx;

    const int lane = tid & 63;
    const int wv = tid >> 6;
    const int rsub = lane >> 3;
    const int slot = lane & 7;
    const int chunk = slot ^ rsub;
    const _Float16* Abase = A + (size_t)(by * 128) * K + chunk * 8;
    const _Float16* Bbase = Wt + (size_t)(bx * 128) * K + chunk * 8;

    const int wm = wv >> 1, wn = wv & 1;
    const int lrow = lane & 15;
    const int lk = lane >> 4;
    const int xorv = lane & 7;
    const int aRowB = (wm * 64 + lrow) * 128;
    const int bRowB = (wn * 64 + lrow) * 128;

    f32x4 acc[4][4] = {};

    auto stage = [&](int buf, int k0) {
#pragma unroll
        for (int t = 0; t < 4; ++t) {
            const int rowb = t * 32 + wv * 8;
            async16(Abase + (size_t)(rowb + rsub) * K + k0, As[buf] + rowb * 128);
            async16(Bbase + (size_t)(rowb + rsub) * K + k0, Bs[buf] + rowb * 128);
        }
    };

    const int nsteps = K >> 6;
    stage(0, 0);
    for (int step = 0; step < nsteps; ++step) {
        const int cur = step & 1;
        if (step + 1 < nsteps) {
            stage(cur ^ 1, (step + 1) * 64);
            asm volatile("s_waitcnt vmcnt(8)" ::: "memory");  // cur's 8 loads done; next's 8 in flight
        } else {
            asm volatile("s_waitcnt vmcnt(0)" ::: "memory");
        }
        __builtin_amdgcn_s_barrier();      // all waves' cur staging visible
#pragma unroll
        for (int kk = 0; kk < 2; ++kk) {
            const int sa = ((kk * 4 + lk) ^ xorv) << 4;
            half8 af[4], bf[4];
#pragma unroll
            for (int mi = 0; mi < 4; ++mi) af[mi] = *(const half8*)(As[cur] + aRowB + mi * 2048 + sa);
#pragma unroll
            for (int ni = 0; ni < 4; ++ni) bf[ni] = *(const half8*)(Bs[cur] + bRowB + ni * 2048 + sa);
#pragma unroll
            for (int mi = 0; mi < 4; ++mi)
#pragma unroll
                for (int ni = 0; ni < 4; ++ni)
                    acc[mi][ni] = __builtin_amdgcn_mfma_f32_16x16x32_f16(af[mi], bf[ni], acc[mi][ni], 0, 0, 0);
        }
        asm volatile("s_waitcnt lgkmcnt(0)" ::: "memory");    // all ds_reads consumed
        __builtin_amdgcn_s_barrier();      // cur free for overwrite next iter
    }

    const int lr4 = (lane >> 4) * 4;
    const int lc = lane & 15;
#pragma unroll
    for (int ni = 0; ni < 4; ++ni) {
        const int colg = bx * 128 + wn * 64 + ni * 16 + lc;
        const float bv = bias[colg];
#pragma unroll
        for (int mi = 0; mi < 4; ++mi) {
            const int rowg = by * 128 + wm * 64 + mi * 16 + lr4;
#pragma unroll
            for (int r = 0; r < 4; ++r) {
                float v = acc[mi][ni][r] + bv;
                if (GELU) v = 0.5f * v * (1.0f + erff(v * 0.70710678118654752440f));
                if (RES) v += res[(size_t)(rowg + r) * N + colg];
                if (OUT_F16) ((_Float16*)Cout)[(size_t)(rowg + r) * N + colg] = (_Float16)v;
                else ((float*)Cout)[(size_t)(rowg + r) * N + colg] = v;
            }
        }
    }
}

// ---------------- MFMA flash attention (session-best configuration) ---------
// Grid 2048, XCD-pinned decode (b%8 = bid&7, h-minor so h-siblings sharing
// inter cachelines co-locate per XCD; FETCH 1.2GB->186MB measured R5).
// Q in registers (A-frag layout), iv/mask loads inside the staging phase
// (drained by the same barrier as K/V staging), 3-term XOR V swizzle
// (bank conflicts 1.5e7->2.1e6 measured R11). ~196us: block-level latency
// floor — 10 structural variants (R5-R18) all measured neutral-or-worse.
__global__ __launch_bounds__(256) void attn_mfma(
        const _Float16* __restrict__ qkv, const float* __restrict__ inter,
        const int* __restrict__ mask, _Float16* __restrict__ o) {
    const int bid = blockIdx.x;
    const int xcd = bid & 7;
    const int s = bid >> 3;
    const int h = s & 7;
    const int qt = (s >> 3) & 7;
    const int b = (s >> 6) * 8 + xcd;
    const int tid = threadIdx.x;
    const int lane = tid & 63;
    const int w = tid >> 6;
    const int l15 = lane & 15, l4 = lane >> 4;

    __shared__ __align__(16) char Ks[8192];
    __shared__ __align__(16) char Vt[8192];
    __shared__ __align__(16) char Ps[8192];

    constexpr size_t QKVROW = 1536;
    // Q in registers: A-fragment for q-row (w*16+l15), chunks l4 / 4+l4
    half8 q0, q1;
    {
        const _Float16* qrow_g = qkv + (size_t)(b * CN + qt * 64 + w * 16 + l15) * QKVROW + h * 64;
        q0 = *(const half8*)(qrow_g + l4 * 8);
        q1 = *(const half8*)(qrow_g + 32 + l4 * 8);
    }

    f32x4 acc_o[4] = {};
    float m_run[4] = {-3e38f, -3e38f, -3e38f, -3e38f};
    float l_run[4] = {0.f, 0.f, 0.f, 0.f};

    // per-r row bases for inter/mask (q row = qt*64 + w*16 + l4*4 + r)
    const int qg0 = qt * 64 + w * 16 + l4 * 4;
    const float* interB[4];
    const int* maskB[4];
#pragma unroll
    for (int r = 0; r < 4; ++r) {
        interB[r] = inter + ((size_t)(b * CN + qg0 + r) * CN) * CH + h;
        maskB[r]  = mask + (size_t)(b * CN + qg0 + r) * CN;
    }

    for (int mt = 0; mt < 8; ++mt) {
        __syncthreads();
        const _Float16* Kg = qkv + (size_t)(b * CN + mt * 64) * QKVROW + 512 + h * 64;
        const _Float16* Vg = Kg + 512;
#pragma unroll
        for (int p = 0; p < 2; ++p) {
            const int f = tid + 256 * p;
            const int r = f >> 3, c = f & 7;
            half8 kv = *(const half8*)(Kg + (size_t)r * QKVROW + c * 8);
            *(half8*)(Ks + r * 128 + ((c ^ (r & 7)) << 4)) = kv;
        }
#pragma unroll
        for (int p = 0; p < 2; ++p) {
            const int f = tid + 256 * p;
            const int m = f >> 3, dc = f & 7;
            half8 vv = *(const half8*)(Vg + (size_t)m * QKVROW + dc * 8);
            const int mc = m >> 3, mo = m & 7;
#pragma unroll
            for (int j = 0; j < 8; ++j) {
                const int d = dc * 8 + j;
                *(_Float16*)(Vt + d * 128 + ((mc ^ (d & 7) ^ dc) << 4) + mo * 2) = vv[j];
            }
        }
        // bias prefetch for this tile (drained with the staging barrier)
        float iv[4][4];
#pragma unroll
        for (int r = 0; r < 4; ++r)
#pragma unroll
            for (int mi = 0; mi < 4; ++mi) {
                const int m = mt * 64 + mi * 16 + l15;
                const float bvv = interB[r][(size_t)m * CH];
                iv[r][mi] = bvv + (maskB[r][m] ? 0.f : -1e9f);
            }
        __syncthreads();

        // QK^T: S[16q x 64m] per wave (Q from regs)
        f32x4 acc_s[4] = {};
#pragma unroll
        for (int step = 0; step < 2; ++step) {
            const half8 aq = step == 0 ? q0 : q1;
            const int ch = step * 4 + l4;
#pragma unroll
            for (int mi = 0; mi < 4; ++mi) {
                const int mrow = mi * 16 + l15;
                half8 bk = *(const half8*)(Ks + mrow * 128 + ((ch ^ (mrow & 7)) << 4));
                acc_s[mi] = __builtin_amdgcn_mfma_f32_16x16x32_f16(aq, bk, acc_s[mi], 0, 0, 0);
            }
        }
        // online softmax (row q = w*16 + l4*4 + r; col m = mi*16 + l15)
#pragma unroll
        for (int r = 0; r < 4; ++r) {
            float pv[4];
            float rmax = -3e38f;
#pragma unroll
            for (int mi = 0; mi < 4; ++mi) {
                float sv = acc_s[mi][r] * 0.125f + iv[r][mi];
                pv[mi] = sv;
                rmax = fmaxf(rmax, sv);
            }
#pragma unroll
            for (int off = 1; off < 16; off <<= 1) rmax = fmaxf(rmax, __shfl_xor(rmax, off));
            const float nm = fmaxf(m_run[r], rmax);
            const float fac = __expf(m_run[r] - nm);
            m_run[r] = nm;
            float ps = 0.f;
#pragma unroll
            for (int mi = 0; mi < 4; ++mi) { float e = __expf(pv[mi] - nm); pv[mi] = e; ps += e; }
#pragma unroll
            for (int off = 1; off < 16; off <<= 1) ps += __shfl_xor(ps, off);
            l_run[r] = l_run[r] * fac + ps;
#pragma unroll
            for (int di = 0; di < 4; ++di) acc_o[di][r] *= fac;
            const int qrow = w * 16 + l4 * 4 + r;
#pragma unroll
            for (int mi = 0; mi < 4; ++mi) {
                const int m = mi * 16 + l15;
                *(_Float16*)(Ps + qrow * 128 + (((m >> 3) ^ (qrow & 7)) << 4) + (m & 7) * 2) = (_Float16)pv[mi];
            }
        }
        // PV: O[16q x 64d] += P @ V^T  (Vt rows = d, k = m; 3-term XOR read)
#pragma unroll
        for (int step = 0; step < 2; ++step) {
            const int qrow = w * 16 + l15;
            const int ch = step * 4 + l4;
            half8 ap = *(const half8*)(Ps + qrow * 128 + ((ch ^ (qrow & 7)) << 4));
#pragma unroll
            for (int di = 0; di < 4; ++di) {
                const int drow = di * 16 + l15;
                half8 bv = *(const half8*)(Vt + drow * 128 + ((ch ^ (drow & 7) ^ (drow >> 3)) << 4));
                acc_o[di] = __builtin_amdgcn_mfma_f32_16x16x32_f16(ap, bv, acc_o[di], 0, 0, 0);
            }
        }
    }
    // epilogue
    _Float16* orow = o + (size_t)(b * CN + qt * 64 + w * 16 + l4 * 4) * CD + h * 64 + l15;
#pragma unroll
    for (int r = 0; r < 4; ++r) {
        const float inv = 1.0f / l_run[r];
#pragma unroll
        for (int di = 0; di < 4; ++di)
            orow[(size_t)r * CD + di * 16] = (_Float16)(acc_o[di][r] * inv);
    }
}

// ---------------- driver ----------------------------------------------------
extern "C" void kernel_launch(void* const* d_in, const int* in_sizes, int n_in,
                              void* d_out, int out_size, void* d_ws, size_t ws_size,
                              hipStream_t stream) {
    const float* x      = (const float*)d_in[0];
    const int*   mask   = (const int*)d_in[1];
    const float* inter  = (const float*)d_in[2];
    const float* w_qkv  = (const float*)d_in[3];
    const float* b_qkv  = (const float*)d_in[4];
    const float* w_out  = (const float*)d_in[5];
    const float* b_out  = (const float*)d_in[6];
    const float* w1     = (const float*)d_in[7];
    const float* b1     = (const float*)d_in[8];
    const float* w2     = (const float*)d_in[9];
    const float* b2     = (const float*)d_in[10];
    const float* g_pre  = (const float*)d_in[11];
    const float* be_pre = (const float*)d_in[12];
    const float* g_post = (const float*)d_in[13];
    const float* be_post= (const float*)d_in[14];
    const float* g_ffn  = (const float*)d_in[15];
    const float* be_ffn = (const float*)d_in[16];
    const float* g_mid  = (const float*)d_in[17];
    const float* be_mid = (const float*)d_in[18];
    float* out = (float*)d_out;

    char* ws = (char*)d_ws;
    const size_t MB = 1ull << 20;
    _Float16* wt_qkv = (_Float16*)(ws + 0 * MB);
    _Float16* wt_out = (_Float16*)(ws + 2 * MB);
    _Float16* wt_w1  = (_Float16*)(ws + 3 * MB);
    _Float16* wt_w2  = (_Float16*)(ws + 5 * MB);
    float*    attended = (float*)(ws + 8 * MB);       // [8,40) fp32
    _Float16* o2h    = (_Float16*)(ws + 40 * MB);     // [40,56) f16
    _Float16* f1b    = (_Float16*)(ws + 64 * MB);     // [64,128) f16 [M,2048]
    _Float16* qkvb   = (_Float16*)(ws + 128 * MB);    // [128,176)
    _Float16* hb     = (_Float16*)(ws + 176 * MB);    // [176,192)
    _Float16* ob     = (_Float16*)(ws + 192 * MB);    // [192,208)
    _Float16* fb     = (_Float16*)(ws + 208 * MB);    // [208,224)

    const int M = CB * CN;  // 16384

    // weight prep
    transpose_f16<<<dim3(1536 / 32, 512 / 32), 256, 0, stream>>>(w_qkv, wt_qkv, 512, 1536);
    transpose_f16<<<dim3(512 / 32, 512 / 32), 256, 0, stream>>>(w_out, wt_out, 512, 512);
    transpose_f16<<<dim3(2048 / 32, 512 / 32), 256, 0, stream>>>(w1, wt_w1, 512, 2048);
    transpose_f16<<<dim3(512 / 32, 2048 / 32), 256, 0, stream>>>(w2, wt_w2, 2048, 512);

    // 1. h = LN(x) -> f16
    ln2_kernel<512, false, true, false><<<M / 4, 256, 0, stream>>>(x, g_pre, be_pre, nullptr, hb);
    // 2. qkv = h @ w_qkv + b_qkv -> f16
    gemm_f16<false, false, true><<<(M / 128) * (1536 / 128), 256, 0, stream>>>(
        hb, wt_qkv, b_qkv, nullptr, qkvb, M, 1536, 512);
    // 3. attention (direct inter+mask) -> o f16
    attn_mfma<<<CB * 8 * 8, 256, 0, stream>>>(qkvb, inter, mask, ob);
    // 4. o2 = o @ w_out + b_out -> f16
    gemm_f16<false, false, true><<<(M / 128) * (512 / 128), 256, 0, stream>>>(
        ob, wt_out, b_out, nullptr, o2h, M, 512, 512);
    // 5+6. attended = LN(o2)+x (fp32); f = LN(attended) (f16)
    ln_post_ffn<<<M / 4, 256, 0, stream>>>(o2h, x, g_post, be_post, g_ffn, be_ffn, attended, fb);
    // 7. f1 = gelu(f @ w1 + b1) -> f16
    gemm_f16<true, false, true><<<(M / 128) * (2048 / 128), 256, 0, stream>>>(
        fb, wt_w1, b1, nullptr, f1b, M, 2048, 512);
    // 8. f1 = LN(f1) in-place
    ln2_kernel<2048, true, true, false><<<M / 4, 256, 0, stream>>>(f1b, g_mid, be_mid, nullptr, f1b);
    // 9. out = f1 @ w2 + b2 + attended -> fp32
    gemm_f16<false, true, false><<<(M / 128) * (512 / 128), 256, 0, stream>>>(
        f1b, wt_w2, b2, attended, out, M, 512, 2048);
}